// Round 5
// baseline (528.927 us; speedup 1.0000x reference)
//
#include <hip/hip_runtime.h>
#include <hip/hip_bf16.h>

#define NN    50000
#define RR    8
#define HIDC  128
#define NHEADS 4
#define EE    640000
#define EE2   200000
#define NCL   8

typedef __hip_bfloat16 bf16;
typedef unsigned short u16;
typedef __attribute__((ext_vector_type(8))) short short8;
typedef __attribute__((ext_vector_type(4))) float floatx4;

__device__ __forceinline__ float us2f(u16 u) {
    return __uint_as_float(((unsigned)u) << 16);
}
__device__ __forceinline__ float bf2f(bf16 v) { return __bfloat162float(v); }
__device__ __forceinline__ u16 f2us(float f) {
    bf16 h = __float2bfloat16(f);
    return *(u16*)&h;
}
__device__ __forceinline__ float ldf(const void* p, int i, bool f32) {
    return f32 ? ((const float*)p)[i] : us2f(((const u16*)p)[i]);
}

// ---------------- dtype sniff: fp32 data viewed as bf16 has exp==0xFF hits ----------------
__global__ __launch_bounds__(1024) void k_sniff(const u16* __restrict__ x, int* __restrict__ flags) {
    __shared__ int cnt;
    if (threadIdx.x == 0) cnt = 0;
    __syncthreads();
    int c = 0;
#pragma unroll
    for (int it = 0; it < 8; it++) {
        ushort4 a = ((const ushort4*)x)[(it * 1024 + threadIdx.x) * 2];
        ushort4 b = ((const ushort4*)x)[(it * 1024 + threadIdx.x) * 2 + 1];
        c += (((a.x >> 7) & 0xFF) == 0xFF) + (((a.y >> 7) & 0xFF) == 0xFF)
           + (((a.z >> 7) & 0xFF) == 0xFF) + (((a.w >> 7) & 0xFF) == 0xFF)
           + (((b.x >> 7) & 0xFF) == 0xFF) + (((b.y >> 7) & 0xFF) == 0xFF)
           + (((b.z >> 7) & 0xFF) == 0xFF) + (((b.w >> 7) & 0xFF) == 0xFF);
    }
    c += __shfl_xor(c, 32); c += __shfl_xor(c, 16); c += __shfl_xor(c, 8);
    c += __shfl_xor(c, 4);  c += __shfl_xor(c, 2);  c += __shfl_xor(c, 1);
    if ((threadIdx.x & 63) == 0) atomicAdd(&cnt, c);
    __syncthreads();
    if (threadIdx.x == 0) { flags[0] = (cnt > 16) ? 1 : 0; flags[1] = 0; }  // [1]=0: internal bf16
}

// ---------------- CSR build ----------------
__global__ void k_zero(int* __restrict__ p, int n) {
    int i = blockIdx.x * 256 + threadIdx.x;
    if (i < n) p[i] = 0;
}
__global__ void k_hist(const int* __restrict__ ei, int* __restrict__ deg) {
    int e = blockIdx.x * 256 + threadIdx.x;
    if (e < EE) atomicAdd(&deg[ei[EE + e]], 1);
}
// 3-phase parallel scan
__global__ __launch_bounds__(256) void k_scan1(const int* __restrict__ deg,
                                               int* __restrict__ bsum) {
    int i = blockIdx.x * 256 + threadIdx.x;
    int v = (i < NN) ? deg[i] : 0;
    __shared__ int red[4];
    int lane = threadIdx.x & 63, w = threadIdx.x >> 6;
#pragma unroll
    for (int off = 32; off; off >>= 1) v += __shfl_xor(v, off);
    if (lane == 0) red[w] = v;
    __syncthreads();
    if (threadIdx.x == 0) bsum[blockIdx.x] = red[0] + red[1] + red[2] + red[3];
}
__global__ __launch_bounds__(256) void k_scan2(const int* __restrict__ bsum,
                                               int* __restrict__ boff,
                                               int* __restrict__ rowptr) {
    __shared__ int s[256];
    int t = threadIdx.x;
    s[t] = (t < 196) ? bsum[t] : 0;
    __syncthreads();
    for (int off = 1; off < 256; off <<= 1) {
        int u = (t >= off) ? s[t - off] : 0;
        __syncthreads();
        s[t] += u;
        __syncthreads();
    }
    if (t < 196) boff[t] = (t == 0) ? 0 : s[t - 1];
    if (t == 255) rowptr[NN] = s[255];
}
__global__ __launch_bounds__(256) void k_scan3(int* __restrict__ deg /*in deg, out cursor*/,
                                               const int* __restrict__ boff,
                                               int* __restrict__ rowptr) {
    __shared__ int s[256];
    int t = threadIdx.x;
    int i = blockIdx.x * 256 + t;
    int v = (i < NN) ? deg[i] : 0;
    s[t] = v;
    __syncthreads();
    for (int off = 1; off < 256; off <<= 1) {
        int u = (t >= off) ? s[t - off] : 0;
        __syncthreads();
        s[t] += u;
        __syncthreads();
    }
    if (i < NN) {
        int val = boff[blockIdx.x] + s[t] - v;  // exclusive
        rowptr[i] = val;
        deg[i] = val;  // cursor copy
    }
}
// pack sr = src*8 + r directly so attn kernels need a single sequential 4B load per edge
__global__ void k_scatter(const int* __restrict__ ei, const int* __restrict__ et,
                          int* __restrict__ cursor, int* __restrict__ elist) {
    int e = blockIdx.x * 256 + threadIdx.x;
    if (e >= EE) return;
    int pos = atomicAdd(&cursor[ei[EE + e]], 1);
    elist[pos] = ei[e] * RR + et[e];
}

// ---------------- qkw[mat][i][h8] = sum_o W[r][i][o] * (q|k)[o][h] ----------------
__global__ void k_qkw(const void* __restrict__ w1, const void* __restrict__ w2,
                      const void* __restrict__ q1, const void* __restrict__ k1,
                      const void* __restrict__ q2, const void* __restrict__ k2,
                      float* __restrict__ qkw, const int* __restrict__ fl) {
    int idx = blockIdx.x * 256 + threadIdx.x;  // 16*128*8 = 16384
    if (idx >= 16384) return;
    const bool f = fl[0] != 0;
    int mat = idx >> 10;
    int i   = (idx >> 3) & 127;
    int h8  = idx & 7;
    const void* W = (mat >= 8) ? w2 : w1;
    const void* qk = (mat >= 8) ? ((h8 < 4) ? q2 : k2) : ((h8 < 4) ? q1 : k1);
    int h = h8 & 3;
    int r = mat & 7;
    float acc = 0.f;
    for (int o = 0; o < HIDC; o++)
        acc += ldf(W, (r * HIDC + i) * HIDC + o, f) * ldf(qk, o * NHEADS + h, f);
    qkw[idx] = acc;
}

// ---------------- W (+qkw cols) -> MFMA B-fragment order: 9 col-tiles ----------------
__global__ void k_wswz(const void* __restrict__ w1, const void* __restrict__ w2,
                       const float* __restrict__ qkw,
                       u16* __restrict__ Wf2, const int* __restrict__ fl) {
    int idx = blockIdx.x * 256 + threadIdx.x;  // 16 * 2304 = 36864
    if (idx >= 36864) return;
    const bool f = fl[0] != 0;
    int mat = idx / 2304, rest = idx % 2304;
    int c = rest >> 8, q = (rest >> 6) & 3, ln = rest & 63;
    int k0 = q * 32 + (ln >> 4) * 8;
    int nn = c * 16 + (ln & 15);
    int r = mat & 7;
    u16 o[8];
    if (c < 8) {
        const void* W = (mat >= 8) ? w2 : w1;
#pragma unroll
        for (int j = 0; j < 8; j++)
            o[j] = f2us(ldf(W, (r * HIDC + k0 + j) * HIDC + nn, f));
    } else {
        int col = nn - 128;  // 0..15
#pragma unroll
        for (int j = 0; j < 8; j++)
            o[j] = (col < 8) ? f2us(qkw[mat * 1024 + (k0 + j) * 8 + col]) : (u16)0;
    }
    u16* dst = Wf2 + (size_t)mat * 18432 + (size_t)(((c * 4 + q) * 64 + ln) * 8);
    *(ushort4*)dst       = ushort4{o[0], o[1], o[2], o[3]};
    *(ushort4*)(dst + 4) = ushort4{o[4], o[5], o[6], o[7]};
}

// ---------------- MFMA xw + s/t: operand-swapped, LDS = input tile only ----------------
// Key trick: for mfma_f32_16x16x32_bf16 the A- and B-fragment layouts are symmetric
// (lane&15 = non-K index, (lane>>4)*8 = K offset). mfma(W_frag, X_frag) computes
// (X*W)^T, whose C-layout gives each lane 4 CONSECUTIVE output channels (8 B) of ONE
// node -> store straight from the accumulator. No Os staging buffer, no LDS round
// trip: LDS drops 52224 -> 16384 B (occupancy was 1 block/CU, LDS-capped).
// s/t tile: lane-group 0 holds s heads 0..3 (float4), group 1 holds t heads.
__global__ __launch_bounds__(512) void k_xw2(const void* __restrict__ X,
                                             const u16* __restrict__ Wf2,
                                             bf16* __restrict__ xw,
                                             float* __restrict__ sbuf,
                                             float* __restrict__ tbuf,
                                             const int* __restrict__ fx,
                                             int layer) {
    __shared__ u16 Xs[64 * 128];        // 16384 B bf16 input tile
    const int tid = threadIdx.x;
    const int n0 = blockIdx.x * 64;
    const bool xf = fx[0] != 0;
    for (int v = tid; v < 2048; v += 512) {
        int row = v >> 5, c4 = (v & 31) * 4, n = n0 + row;
        ushort4 o = {0, 0, 0, 0};
        if (n < NN) {
            if (xf) {
                float4 hv = *(const float4*)((const float*)X + (size_t)n * HIDC + c4);
                o = ushort4{f2us(hv.x), f2us(hv.y), f2us(hv.z), f2us(hv.w)};
            } else {
                o = *(const ushort4*)((const u16*)X + (size_t)n * HIDC + c4);
            }
        }
        *(ushort4*)&Xs[row * 128 + c4] = o;
    }
    __syncthreads();
    const int w = tid >> 6, lane = tid & 63;
    const int wr = w & 3;   // row-group: rows 16*wr .. 16*wr+15
    const int rh = w >> 2;  // relation half: r in [4*rh, 4*rh+4)
    const int g = lane >> 4;             // k-group 0..3 / channel-group in D^T
    const int node = 16 * wr + (lane & 15);
    const int n = n0 + node;
    const bool nok = (n < NN);
    short8 af[4];
#pragma unroll
    for (int q = 0; q < 4; q++)
        af[q] = *(const short8*)&Xs[node * 128 + q * 32 + g * 8];
    for (int rr = 0; rr < 4; rr++) {
        const int r = rh * 4 + rr;
        const u16* Wfr = Wf2 + (size_t)(layer * 8 + r) * 18432;
        u16* xrow = (u16*)xw + (size_t)(n * RR + r) * HIDC;
#pragma unroll
        for (int c = 0; c < 9; c++) {
            floatx4 acc = {0.f, 0.f, 0.f, 0.f};
#pragma unroll
            for (int q = 0; q < 4; q++) {
                short8 bfr = *(const short8*)&Wfr[(size_t)(((c * 4 + q) * 64 + lane) * 8)];
                // swapped operands: D^T -> lane holds node (lane&15), channels c*16+g*4+reg
                acc = __builtin_amdgcn_mfma_f32_16x16x32_bf16(bfr, af[q], acc, 0, 0, 0);
            }
            if (c < 8) {
                if (nok) {
                    ushort4 o = {f2us(acc[0]), f2us(acc[1]), f2us(acc[2]), f2us(acc[3])};
                    *(ushort4*)(xrow + c * 16 + g * 4) = o;
                }
            } else {
                // channels 0..3 = s heads, 4..7 = t heads, 8..15 = zero pad
                if (nok && g < 2) {
                    float* dstp = (g == 0) ? sbuf : tbuf;
                    *(float4*)&dstp[(size_t)(n * RR + r) * 4] =
                        float4{acc[0], acc[1], acc[2], acc[3]};
                }
            }
        }
    }
}

// ---------------- score pass: weights only, global max (no online rescale) ----------------
// Per dst node (16-lane group): stage sb row in LDS, gather tb per edge, leaky-relu,
// width-16 reduce with GLOBAL max, store unnormalized ex per edge (abuf, coalesced)
// and 1/l per (node, head) (linv). Latency hidden purely by TLP (no big gathers here).
__global__ __launch_bounds__(256) void k_score(const int* __restrict__ rowptr,
                                               const int* __restrict__ srlist,
                                               const float* __restrict__ sb,
                                               const float* __restrict__ tb,
                                               float* __restrict__ abuf,
                                               float* __restrict__ linv) {
    __shared__ float sbs[16][8][4];
    const int tid = threadIdx.x;
    const int grp = tid >> 4, sl = tid & 15;
    const int d = blockIdx.x * 16 + grp;    // grid exact: 3125*16 = 50000
    const int start = rowptr[d], end = rowptr[d + 1];
    if (sl < 8)
        *(float4*)&sbs[grp][sl][0] = *(const float4*)&sb[(size_t)(d * RR + sl) * 4];
    // wave-local LDS write->read: DS ops in-order within a wave
    const int nE = end - start;
    float m0 = -1e30f, m1 = -1e30f, m2 = -1e30f, m3 = -1e30f;
    float l0 = 0.f, l1 = 0.f, l2 = 0.f, l3 = 0.f;
    if (nE <= 16) {
        // single-chunk fast path (~85% of nodes): alpha stays in registers
        float a0, a1, a2, a3;
        if (sl < nE) {
            int sr = srlist[start + sl];
            int r = sr & 7;
            float4 tj = *(const float4*)&tb[(size_t)sr * 4];
            a0 = sbs[grp][r][0] + tj.x; a0 = a0 >= 0.f ? a0 : 0.2f * a0;
            a1 = sbs[grp][r][1] + tj.y; a1 = a1 >= 0.f ? a1 : 0.2f * a1;
            a2 = sbs[grp][r][2] + tj.z; a2 = a2 >= 0.f ? a2 : 0.2f * a2;
            a3 = sbs[grp][r][3] + tj.w; a3 = a3 >= 0.f ? a3 : 0.2f * a3;
        } else { a0 = a1 = a2 = a3 = -1e30f; }
        float c0m = a0, c1m = a1, c2m = a2, c3m = a3;
#pragma unroll
        for (int off = 8; off; off >>= 1) {
            c0m = fmaxf(c0m, __shfl_xor(c0m, off));
            c1m = fmaxf(c1m, __shfl_xor(c1m, off));
            c2m = fmaxf(c2m, __shfl_xor(c2m, off));
            c3m = fmaxf(c3m, __shfl_xor(c3m, off));
        }
        m0 = fmaxf(c0m, -1e30f); m1 = c1m; m2 = c2m; m3 = c3m;
        float e0 = 0.f, e1 = 0.f, e2 = 0.f, e3 = 0.f;
        if (sl < nE) {
            e0 = __expf(a0 - m0); e1 = __expf(a1 - m1);
            e2 = __expf(a2 - m2); e3 = __expf(a3 - m3);
            *(float4*)&abuf[(size_t)(start + sl) * 4] = float4{e0, e1, e2, e3};
        }
        l0 = e0; l1 = e1; l2 = e2; l3 = e3;
#pragma unroll
        for (int off = 8; off; off >>= 1) {
            l0 += __shfl_xor(l0, off);
            l1 += __shfl_xor(l1, off);
            l2 += __shfl_xor(l2, off);
            l3 += __shfl_xor(l3, off);
        }
    } else {
        // pass 1: alpha -> abuf, track global max
        for (int c0 = start; c0 < end; c0 += 16) {
            int n = end - c0; if (n > 16) n = 16;
            float a0, a1, a2, a3;
            if (sl < n) {
                int sr = srlist[c0 + sl];
                int r = sr & 7;
                float4 tj = *(const float4*)&tb[(size_t)sr * 4];
                a0 = sbs[grp][r][0] + tj.x; a0 = a0 >= 0.f ? a0 : 0.2f * a0;
                a1 = sbs[grp][r][1] + tj.y; a1 = a1 >= 0.f ? a1 : 0.2f * a1;
                a2 = sbs[grp][r][2] + tj.z; a2 = a2 >= 0.f ? a2 : 0.2f * a2;
                a3 = sbs[grp][r][3] + tj.w; a3 = a3 >= 0.f ? a3 : 0.2f * a3;
                *(float4*)&abuf[(size_t)(c0 + sl) * 4] = float4{a0, a1, a2, a3};
            } else { a0 = a1 = a2 = a3 = -1e30f; }
            m0 = fmaxf(m0, a0); m1 = fmaxf(m1, a1);
            m2 = fmaxf(m2, a2); m3 = fmaxf(m3, a3);
        }
#pragma unroll
        for (int off = 8; off; off >>= 1) {
            m0 = fmaxf(m0, __shfl_xor(m0, off));
            m1 = fmaxf(m1, __shfl_xor(m1, off));
            m2 = fmaxf(m2, __shfl_xor(m2, off));
            m3 = fmaxf(m3, __shfl_xor(m3, off));
        }
        // pass 2: ex = exp(alpha - m) -> abuf (in place), accumulate l
        for (int c0 = start; c0 < end; c0 += 16) {
            int n = end - c0; if (n > 16) n = 16;
            float e0 = 0.f, e1 = 0.f, e2 = 0.f, e3 = 0.f;
            if (sl < n) {
                float4 a = *(const float4*)&abuf[(size_t)(c0 + sl) * 4];
                e0 = __expf(a.x - m0); e1 = __expf(a.y - m1);
                e2 = __expf(a.z - m2); e3 = __expf(a.w - m3);
                *(float4*)&abuf[(size_t)(c0 + sl) * 4] = float4{e0, e1, e2, e3};
            }
            l0 += e0; l1 += e1; l2 += e2; l3 += e3;
        }
#pragma unroll
        for (int off = 8; off; off >>= 1) {
            l0 += __shfl_xor(l0, off);
            l1 += __shfl_xor(l1, off);
            l2 += __shfl_xor(l2, off);
            l3 += __shfl_xor(l3, off);
        }
    }
    if (sl == 0) {
        *(float4*)&linv[(size_t)d * 4] =
            float4{1.f / (l0 + 1e-16f), 1.f / (l1 + 1e-16f),
                   1.f / (l2 + 1e-16f), 1.f / (l3 + 1e-16f)};
    }
}

// ---------------- aggregation pump: gathers only on the critical path ----------------
// Per dst node (16-lane group): coalesced srlist+ex loads -> LDS -> 8-deep batches of
// independent 256B row gathers -> FMA. No shuffles/exp/rescale in the loop (global max
// was used in k_score). Masked lanes gather row 0 with weight 0 (L1-hot, branch-free).
__global__ __launch_bounds__(256) void k_agg(const int* __restrict__ rowptr,
                                             const int* __restrict__ srlist,
                                             const float* __restrict__ abuf,
                                             const float* __restrict__ linvb,
                                             const bf16* __restrict__ xw,
                                             const void* __restrict__ b,
                                             const void* __restrict__ g,
                                             const void* __restrict__ bb,
                                             const u16* __restrict__ hprev,
                                             u16* __restrict__ hout,
                                             const int* __restrict__ fl) {
    __shared__ int   srs[16][16];
    __shared__ float exs[16][17][4];   // padded: group stride 68 floats
    const int tid = threadIdx.x;
    const int grp = tid >> 4;
    const int sl  = tid & 15;
    const int hh  = sl >> 2;
    const int d   = blockIdx.x * 16 + grp;
    const bool f = fl[0] != 0;
    const int start = rowptr[d], end = rowptr[d + 1];
    float acc[8];
#pragma unroll
    for (int i = 0; i < 8; i++) acc[i] = 0.f;
    for (int c0 = start; c0 < end; c0 += 16) {
        int n = end - c0;
        if (n > 16) n = 16;
        int sr = 0;
        float4 e4 = {0.f, 0.f, 0.f, 0.f};
        if (sl < n) {
            sr = srlist[c0 + sl];
            e4 = *(const float4*)&abuf[(size_t)(c0 + sl) * 4];
        }
        srs[grp][sl] = sr;
        *(float4*)&exs[grp][sl][0] = e4;
        // batch 0: edges 0..7 (branch-free; padding rows are 0-weight, L1-hot)
        {
            short8 u[8]; float wv[8];
#pragma unroll
            for (int t = 0; t < 8; t++) {
                int s = srs[grp][t];
                wv[t] = exs[grp][t][hh];
                u[t] = *(const short8*)((const u16*)xw + (size_t)s * HIDC + sl * 8);
            }
#pragma unroll
            for (int t = 0; t < 8; t++)
#pragma unroll
                for (int i = 0; i < 8; i++) acc[i] += wv[t] * us2f((u16)u[t][i]);
        }
        if (n > 8) {
            short8 u[8]; float wv[8];
#pragma unroll
            for (int t = 0; t < 8; t++) {
                int s = srs[grp][8 + t];
                wv[t] = exs[grp][8 + t][hh];
                u[t] = *(const short8*)((const u16*)xw + (size_t)s * HIDC + sl * 8);
            }
#pragma unroll
            for (int t = 0; t < 8; t++)
#pragma unroll
                for (int i = 0; i < 8; i++) acc[i] += wv[t] * us2f((u16)u[t][i]);
        }
    }
    float inv = linvb[(size_t)d * 4 + hh];
    float v[8];
#pragma unroll
    for (int i = 0; i < 8; i++)
        v[i] = fmaxf(acc[i] * inv + ldf(b, sl * 8 + i, f), 0.f);
    float sum = 0.f;
#pragma unroll
    for (int i = 0; i < 8; i++) sum += v[i];
#pragma unroll
    for (int off = 8; off; off >>= 1) sum += __shfl_xor(sum, off);
    float mean = sum * (1.f / 128.f);
    float sq = 0.f;
#pragma unroll
    for (int i = 0; i < 8; i++) { v[i] -= mean; sq += v[i] * v[i]; }
#pragma unroll
    for (int off = 8; off; off >>= 1) sq += __shfl_xor(sq, off);
    float rstd = rsqrtf(sq * (1.f / 128.f) + 1e-5f);
    short8 o;
#pragma unroll
    for (int i = 0; i < 8; i++) {
        float y = v[i] * rstd * ldf(g, sl * 8 + i, f) + ldf(bb, sl * 8 + i, f);
        o[i] = (short)f2us(y);
    }
    if (hprev) {
        short8 hv = *(const short8*)&hprev[(size_t)d * HIDC + sl * 8];
#pragma unroll
        for (int i = 0; i < 8; i++)
            o[i] = (short)f2us(us2f((u16)o[i]) + us2f((u16)hv[i]));
    }
    *(short8*)&hout[(size_t)d * HIDC + sl * 8] = o;
}

// ---------------- mw1 + mw2 -> B-fragment order (bf16) for MFMA decode ----------------
__global__ void k_dswz(const void* __restrict__ mw1, const void* __restrict__ mw2,
                       u16* __restrict__ Wf, const int* __restrict__ fl) {
    int idx = blockIdx.x * 256 + threadIdx.x;  // 0..4351
    if (idx >= 4352) return;
    const bool f = fl[0] != 0;
    u16 o[8];
    if (idx < 4096) {
        int c = idx >> 9, q = (idx >> 6) & 7, ln = idx & 63;
        int k0 = q * 32 + (ln >> 4) * 8;
        int nn = c * 16 + (ln & 15);
#pragma unroll
        for (int j = 0; j < 8; j++)
            o[j] = f2us(ldf(mw1, (k0 + j) * HIDC + nn, f));
    } else {
        int fidx = idx - 4096;           // q*64 + lane
        int q = fidx >> 6, ln = fidx & 63;
        int k0 = q * 32 + (ln >> 4) * 8;
        int nn = ln & 15;
#pragma unroll
        for (int j = 0; j < 8; j++)
            o[j] = (nn < 8) ? f2us(ldf(mw2, (k0 + j) * NCL + nn, f)) : (u16)0;
    }
    *(ushort4*)&Wf[idx * 8]     = ushort4{o[0], o[1], o[2], o[3]};
    *(ushort4*)&Wf[idx * 8 + 4] = ushort4{o[4], o[5], o[6], o[7]};
}

// ---------------- decode: barrier-free, direct bf16 A-fragment gathers ----------------
__global__ __launch_bounds__(256) void k_decode2(const u16* __restrict__ h,
                                                 const int* __restrict__ edges,
                                                 const u16* __restrict__ Wf,
                                                 const void* __restrict__ mb1,
                                                 const void* __restrict__ mb2,
                                                 void* __restrict__ out,
                                                 const int* __restrict__ fl) {
    __shared__ u16 zsu[64 * 136];   // 17.4 KB, wave-local rows only
    const int tid = threadIdx.x;
    const bool f = fl[0] != 0;
    const int p0 = blockIdx.x * 64;
    const int w = tid >> 6, lane = tid & 63;
    const int m = 16 * w + (lane & 15);   // row in 64-tile
    const int g = lane >> 4;              // k-group 0..3
    const int na = edges[(size_t)(p0 + m) * 2];
    const int nb = edges[(size_t)(p0 + m) * 2 + 1];
    short8 af[8];
#pragma unroll
    for (int q = 0; q < 8; q++) {
        int k0 = q * 32 + g * 8;          // 0..248
        af[q] = *(const short8*)(h + (size_t)((k0 >> 7) ? nb : na) * HIDC + (k0 & 127));
    }
#pragma unroll
    for (int c = 0; c < 8; c++) {
        floatx4 acc = {0.f, 0.f, 0.f, 0.f};
#pragma unroll
        for (int q = 0; q < 8; q++) {
            short8 bfr = *(const short8*)&Wf[(size_t)(((c * 8 + q) * 64 + lane) * 8)];
            acc = __builtin_amdgcn_mfma_f32_16x16x32_bf16(af[q], bfr, acc, 0, 0, 0);
        }
        int col = c * 16 + (lane & 15);
        float bv = ldf(mb1, col, f);
#pragma unroll
        for (int reg = 0; reg < 4; reg++) {
            int p = 16 * w + (lane >> 4) * 4 + reg;
            float z = acc[reg] + bv;
            zsu[p * 136 + col] = f2us(0.5f * z * (1.f + erff(z * 0.70710678118654752f)));
        }
    }
    // second GEMM: rows wave-local -> no barrier
    floatx4 acc2 = {0.f, 0.f, 0.f, 0.f};
#pragma unroll
    for (int q = 0; q < 4; q++) {
        short8 af2 = *(const short8*)&zsu[m * 136 + q * 32 + g * 8];
        short8 bfr2 = *(const short8*)&Wf[32768 + (size_t)((q * 64 + lane) * 8)];
        acc2 = __builtin_amdgcn_mfma_f32_16x16x32_bf16(af2, bfr2, acc2, 0, 0, 0);
    }
    int col16 = lane & 15;
    if (col16 < 8) {
        float bv2 = ldf(mb2, col16, f);
#pragma unroll
        for (int reg = 0; reg < 4; reg++) {
            int p = 16 * w + (lane >> 4) * 4 + reg;
            float sv = acc2[reg] + bv2;
            size_t oi = (size_t)(p0 + p) * NCL + col16;
            if (f) ((float*)out)[oi] = sv;
            else   ((bf16*)out)[oi] = __float2bfloat16(sv);
        }
    }
}

extern "C" void kernel_launch(void* const* d_in, const int* in_sizes, int n_in,
                              void* d_out, int out_size, void* d_ws, size_t ws_size,
                              hipStream_t stream) {
    (void)in_sizes; (void)n_in; (void)out_size; (void)ws_size;
    const void* x    = d_in[0];
    const int* ei    = (const int*)d_in[1];
    const int* et    = (const int*)d_in[2];
    const int* edges = (const int*)d_in[3];
    const void* w1 = d_in[4];
    const void* q1 = d_in[5];
    const void* k1 = d_in[6];
    const void* b1 = d_in[7];
    const void* w2 = d_in[8];
    const void* q2 = d_in[9];
    const void* k2 = d_in[10];
    const void* b2 = d_in[11];
    const void* ln1g = d_in[12];
    const void* ln1b = d_in[13];
    const void* ln2g = d_in[14];
    const void* ln2b = d_in[15];
    const void* mw1 = d_in[16];
    const void* mb1 = d_in[17];
    const void* mw2 = d_in[18];
    const void* mb2 = d_in[19];

    // workspace layout — within round-3-proven bound (<= 169,425,560 B)
    char* ws = (char*)d_ws;
    bf16* xwb   = (bf16*)ws;                      // [0, 102,400,000)
    u16* Wf     = (u16*)ws;                       // ALIAS xwb: k_dswz runs after last xwb read (69,632 B)
    float* sbuf = (float*)(ws + 102400000);       // 6.4 MB
    float* tbuf = (float*)(ws + 108800000);       // 6.4 MB
    u16* h1     = (u16*)(ws + 115200000);         // 12.8 MB (bf16), region ends 128,000,000
    float* abuf = (float*)(ws + 128000000);       // EE*16 B = 10,240,000 -> ends 138,240,000
    float* linv = (float*)(ws + 138240000);       // NN*16 B = 800,000 -> ends 139,040,000
    u16* hsum   = (u16*)(ws + 140800000);         // 12.8 MB (bf16)
    u16* Wf2    = (u16*)(ws + 153600000);         // 589,824 B
    int* rowptr = (int*)(ws + 166400000);         // NN+1 ints
    int* cursor = (int*)(ws + 166600016);         // NN ints
    int* elist  = (int*)(ws + 166800016);         // EE ints (packed sr = src*8+r)
    float* qkw  = (float*)(ws + 169360016);       // 65,536 B -> ends 169,425,552
    int* bsum   = (int*)qkw;                      // ALIAS qkw: scan phases finish before k_qkw writes
    int* boff   = bsum + 256;
    int* flags  = (int*)(ws + 169425552);         // 8 B -> ends 169,425,560 (proven)

    k_sniff<<<1, 1024, 0, stream>>>((const u16*)x, flags);

    // CSR build (parallel 3-phase scan) + weight preprocessing
    k_zero<<<196, 256, 0, stream>>>(cursor, NN);
    k_hist<<<2500, 256, 0, stream>>>(ei, cursor);
    k_scan1<<<196, 256, 0, stream>>>(cursor, bsum);
    k_scan2<<<1, 256, 0, stream>>>(bsum, boff, rowptr);
    k_scan3<<<196, 256, 0, stream>>>(cursor, boff, rowptr);
    k_scatter<<<2500, 256, 0, stream>>>(ei, et, cursor, elist);
    k_qkw<<<64, 256, 0, stream>>>(w1, w2, q1, k1, q2, k2, qkw, flags);
    k_wswz<<<144, 256, 0, stream>>>(w1, w2, qkw, Wf2, flags);

    for (int layer = 0; layer < 2; ++layer) {
        const void* b  = layer ? b2 : b1;
        const void* lg = layer ? ln2g : ln1g;
        const void* lb = layer ? ln2b : ln1b;
        k_xw2<<<782, 512, 0, stream>>>(layer ? (const void*)h1 : x, Wf2, xwb,
                                       sbuf, tbuf,
                                       layer ? flags + 1 : flags, layer);
        k_score<<<3125, 256, 0, stream>>>(rowptr, elist, sbuf, tbuf, abuf, linv);
        k_agg<<<3125, 256, 0, stream>>>(rowptr, elist, abuf, linv, xwb,
                                        b, lg, lb,
                                        layer ? h1 : (const u16*)nullptr,
                                        layer ? hsum : h1, flags);
    }
    // decode weight swizzle into xwb space (xwb dead after attn L1)
    k_dswz<<<17, 256, 0, stream>>>(mw1, mw2, Wf, flags);
    k_decode2<<<3125, 256, 0, stream>>>(hsum, edges, Wf, mb1, mb2, d_out, flags);
}

// Round 6
// 469.212 us; speedup vs baseline: 1.1273x; 1.1273x over previous
//
#include <hip/hip_runtime.h>
#include <hip/hip_bf16.h>

#define NN    50000
#define RR    8
#define HIDC  128
#define NHEADS 4
#define EE    640000
#define EE2   200000
#define NCL   8

typedef __hip_bfloat16 bf16;
typedef unsigned short u16;
typedef __attribute__((ext_vector_type(8))) short short8;
typedef __attribute__((ext_vector_type(4))) float floatx4;

__device__ __forceinline__ float us2f(u16 u) {
    return __uint_as_float(((unsigned)u) << 16);
}
__device__ __forceinline__ float bf2f(bf16 v) { return __bfloat162float(v); }
__device__ __forceinline__ u16 f2us(float f) {
    bf16 h = __float2bfloat16(f);
    return *(u16*)&h;
}
__device__ __forceinline__ float ldf(const void* p, int i, bool f32) {
    return f32 ? ((const float*)p)[i] : us2f(((const u16*)p)[i]);
}

// ---------------- fused: cursor zero (blocks 0..48) + dtype sniff (block 49) ----------------
__global__ __launch_bounds__(1024) void k_zs(const u16* __restrict__ x,
                                             int* __restrict__ flags,
                                             int* __restrict__ p) {
    if (blockIdx.x < 49) {
        int i = blockIdx.x * 1024 + threadIdx.x;
        if (i < NN) p[i] = 0;
        return;
    }
    __shared__ int cnt;
    if (threadIdx.x == 0) cnt = 0;
    __syncthreads();
    int c = 0;
#pragma unroll
    for (int it = 0; it < 8; it++) {
        ushort4 a = ((const ushort4*)x)[(it * 1024 + threadIdx.x) * 2];
        ushort4 b = ((const ushort4*)x)[(it * 1024 + threadIdx.x) * 2 + 1];
        c += (((a.x >> 7) & 0xFF) == 0xFF) + (((a.y >> 7) & 0xFF) == 0xFF)
           + (((a.z >> 7) & 0xFF) == 0xFF) + (((a.w >> 7) & 0xFF) == 0xFF)
           + (((b.x >> 7) & 0xFF) == 0xFF) + (((b.y >> 7) & 0xFF) == 0xFF)
           + (((b.z >> 7) & 0xFF) == 0xFF) + (((b.w >> 7) & 0xFF) == 0xFF);
    }
    c += __shfl_xor(c, 32); c += __shfl_xor(c, 16); c += __shfl_xor(c, 8);
    c += __shfl_xor(c, 4);  c += __shfl_xor(c, 2);  c += __shfl_xor(c, 1);
    if ((threadIdx.x & 63) == 0) atomicAdd(&cnt, c);
    __syncthreads();
    if (threadIdx.x == 0) { flags[0] = (cnt > 16) ? 1 : 0; flags[1] = 0; }
}

__global__ void k_hist(const int* __restrict__ ei, int* __restrict__ deg) {
    int e = blockIdx.x * 256 + threadIdx.x;
    if (e < EE) atomicAdd(&deg[ei[EE + e]], 1);
}

// ---------------- fused: scan1 (blocks 0..195) + qkw (blocks 196..259) ----------------
__global__ __launch_bounds__(256) void k_s1q(const int* __restrict__ deg,
                                             int* __restrict__ bsum,
                                             const void* __restrict__ w1, const void* __restrict__ w2,
                                             const void* __restrict__ q1, const void* __restrict__ k1,
                                             const void* __restrict__ q2, const void* __restrict__ k2,
                                             float* __restrict__ qkw, const int* __restrict__ fl) {
    if (blockIdx.x < 196) {
        int i = blockIdx.x * 256 + threadIdx.x;
        int v = (i < NN) ? deg[i] : 0;
        __shared__ int red[4];
        int lane = threadIdx.x & 63, w = threadIdx.x >> 6;
#pragma unroll
        for (int off = 32; off; off >>= 1) v += __shfl_xor(v, off);
        if (lane == 0) red[w] = v;
        __syncthreads();
        if (threadIdx.x == 0) bsum[blockIdx.x] = red[0] + red[1] + red[2] + red[3];
        return;
    }
    int idx = (blockIdx.x - 196) * 256 + threadIdx.x;  // 0..16383
    const bool f = fl[0] != 0;
    int mat = idx >> 10;
    int i   = (idx >> 3) & 127;
    int h8  = idx & 7;
    const void* W = (mat >= 8) ? w2 : w1;
    const void* qk = (mat >= 8) ? ((h8 < 4) ? q2 : k2) : ((h8 < 4) ? q1 : k1);
    int h = h8 & 3;
    int r = mat & 7;
    float acc = 0.f;
    for (int o = 0; o < HIDC; o++)
        acc += ldf(W, (r * HIDC + i) * HIDC + o, f) * ldf(qk, o * NHEADS + h, f);
    qkw[idx] = acc;
}

__global__ __launch_bounds__(256) void k_scan2(const int* __restrict__ bsum,
                                               int* __restrict__ boff,
                                               int* __restrict__ rowptr) {
    __shared__ int s[256];
    int t = threadIdx.x;
    s[t] = (t < 196) ? bsum[t] : 0;
    __syncthreads();
    for (int off = 1; off < 256; off <<= 1) {
        int u = (t >= off) ? s[t - off] : 0;
        __syncthreads();
        s[t] += u;
        __syncthreads();
    }
    if (t < 196) boff[t] = (t == 0) ? 0 : s[t - 1];
    if (t == 255) rowptr[NN] = s[255];
}

// ---------------- fused: scan3 (blocks 0..195) + wswz (blocks 196..339) ----------------
__global__ __launch_bounds__(256) void k_s3w(int* __restrict__ deg /*in deg, out cursor*/,
                                             const int* __restrict__ boff,
                                             int* __restrict__ rowptr,
                                             const void* __restrict__ w1, const void* __restrict__ w2,
                                             const float* __restrict__ qkw,
                                             u16* __restrict__ Wf2, const int* __restrict__ fl) {
    if (blockIdx.x < 196) {
        __shared__ int s[256];
        int t = threadIdx.x;
        int i = blockIdx.x * 256 + t;
        int v = (i < NN) ? deg[i] : 0;
        s[t] = v;
        __syncthreads();
        for (int off = 1; off < 256; off <<= 1) {
            int u = (t >= off) ? s[t - off] : 0;
            __syncthreads();
            s[t] += u;
            __syncthreads();
        }
        if (i < NN) {
            int val = boff[blockIdx.x] + s[t] - v;  // exclusive
            rowptr[i] = val;
            deg[i] = val;  // cursor copy
        }
        return;
    }
    int idx = (blockIdx.x - 196) * 256 + threadIdx.x;  // 0..36863
    const bool f = fl[0] != 0;
    int mat = idx / 2304, rest = idx % 2304;
    int c = rest >> 8, q = (rest >> 6) & 3, ln = rest & 63;
    int k0 = q * 32 + (ln >> 4) * 8;
    int nn = c * 16 + (ln & 15);
    int r = mat & 7;
    u16 o[8];
    if (c < 8) {
        const void* W = (mat >= 8) ? w2 : w1;
#pragma unroll
        for (int j = 0; j < 8; j++)
            o[j] = f2us(ldf(W, (r * HIDC + k0 + j) * HIDC + nn, f));
    } else {
        int col = nn - 128;  // 0..15
#pragma unroll
        for (int j = 0; j < 8; j++)
            o[j] = (col < 8) ? f2us(qkw[mat * 1024 + (k0 + j) * 8 + col]) : (u16)0;
    }
    u16* dst = Wf2 + (size_t)mat * 18432 + (size_t)(((c * 4 + q) * 64 + ln) * 8);
    *(ushort4*)dst       = ushort4{o[0], o[1], o[2], o[3]};
    *(ushort4*)(dst + 4) = ushort4{o[4], o[5], o[6], o[7]};
}

// pack sr = src*8 + r directly so attn kernels need a single sequential 4B load per edge
__global__ void k_scatter(const int* __restrict__ ei, const int* __restrict__ et,
                          int* __restrict__ cursor, int* __restrict__ elist) {
    int e = blockIdx.x * 256 + threadIdx.x;
    if (e >= EE) return;
    int pos = atomicAdd(&cursor[ei[EE + e]], 1);
    elist[pos] = ei[e] * RR + et[e];
}

// ---------------- MFMA xw + s/t: Os-staged coalesced stores, Os ALIASED onto Xs ----------------
// r4 structure (proven 61 us, coalesced 16B stores, WRITE=121MB) with the LDS fix:
// af fragments are register-resident before the r-loop, so Xs is dead after barrier 2.
// Os (8 waves x 16 rows x 136) overlays the same allocation -> LDS 52224 -> 34816 B.
__global__ __launch_bounds__(512) void k_xw2(const void* __restrict__ X,
                                             const u16* __restrict__ Wf2,
                                             bf16* __restrict__ xw,
                                             float* __restrict__ sbuf,
                                             float* __restrict__ tbuf,
                                             const int* __restrict__ fx,
                                             int layer) {
    __shared__ u16 U[8 * 16 * 136];     // 34816 B union: [staging Xs 64x136 | per-wave Os]
    u16* Xs = U;
    const int tid = threadIdx.x;
    const int n0 = blockIdx.x * 64;
    const bool xf = fx[0] != 0;
    for (int v = tid; v < 2048; v += 512) {
        int row = v >> 5, c4 = (v & 31) * 4, n = n0 + row;
        ushort4 o = {0, 0, 0, 0};
        if (n < NN) {
            if (xf) {
                float4 hv = *(const float4*)((const float*)X + (size_t)n * HIDC + c4);
                o = ushort4{f2us(hv.x), f2us(hv.y), f2us(hv.z), f2us(hv.w)};
            } else {
                o = *(const ushort4*)((const u16*)X + (size_t)n * HIDC + c4);
            }
        }
        *(ushort4*)&Xs[row * 136 + c4] = o;
    }
    __syncthreads();
    const int w = tid >> 6, lane = tid & 63;
    const int wr = w & 3;   // row-group: rows 16*wr .. 16*wr+15
    const int rh = w >> 2;  // relation half: r in [4*rh, 4*rh+4)
    short8 af[4];
#pragma unroll
    for (int q = 0; q < 4; q++)
        af[q] = *(const short8*)&Xs[(16 * wr + (lane & 15)) * 136 + q * 32 + (lane >> 4) * 8];
    __syncthreads();   // all waves done reading Xs before Os overwrites it
    u16* Ow = U + w * 2176;             // per-wave 16 x 136 tile
    for (int rr = 0; rr < 4; rr++) {
        const int r = rh * 4 + rr;
        const u16* Wfr = Wf2 + (size_t)(layer * 8 + r) * 18432;
#pragma unroll
        for (int c = 0; c < 9; c++) {
            floatx4 acc = {0.f, 0.f, 0.f, 0.f};
#pragma unroll
            for (int q = 0; q < 4; q++) {
                short8 bfr = *(const short8*)&Wfr[(size_t)(((c * 4 + q) * 64 + lane) * 8)];
                acc = __builtin_amdgcn_mfma_f32_16x16x32_bf16(af[q], bfr, acc, 0, 0, 0);
            }
            if (c < 8) {
                int col = c * 16 + (lane & 15);
#pragma unroll
                for (int reg = 0; reg < 4; reg++) {
                    int lp = (lane >> 4) * 4 + reg;
                    Ow[lp * 136 + col] = f2us(acc[reg]);
                }
            } else {
                int cl = lane & 15;  // 0..3 -> s heads, 4..7 -> t heads
                if (cl < 8) {
                    float* dstp = (cl < 4) ? sbuf : tbuf;
                    int h = cl & 3;
#pragma unroll
                    for (int reg = 0; reg < 4; reg++) {
                        int p = 16 * wr + (lane >> 4) * 4 + reg;
                        int n = n0 + p;
                        if (n < NN) dstp[(size_t)(n * RR + r) * 4 + h] = acc[reg];
                    }
                }
            }
        }
        // wave-local coalesced store: 16 rows x 256 B, 4 iters x 16 B/lane
#pragma unroll
        for (int i = 0; i < 4; i++) {
            int v = i * 64 + lane;       // 0..255
            int lrow = v >> 4;           // 0..15
            int c8 = (v & 15) * 8;       // 0..120
            int n = n0 + 16 * wr + lrow;
            if (n < NN) {
                short8 hv = *(const short8*)&Ow[lrow * 136 + c8];
                *(short8*)((u16*)xw + (size_t)(n * RR + r) * HIDC + c8) = hv;
            }
        }
    }
}

// ---------------- score pass: weights only, global max (no online rescale) ----------------
__global__ __launch_bounds__(256) void k_score(const int* __restrict__ rowptr,
                                               const int* __restrict__ srlist,
                                               const float* __restrict__ sb,
                                               const float* __restrict__ tb,
                                               float* __restrict__ abuf,
                                               float* __restrict__ linv) {
    __shared__ float sbs[16][8][4];
    const int tid = threadIdx.x;
    const int grp = tid >> 4, sl = tid & 15;
    const int d = blockIdx.x * 16 + grp;    // grid exact: 3125*16 = 50000
    const int start = rowptr[d], end = rowptr[d + 1];
    if (sl < 8)
        *(float4*)&sbs[grp][sl][0] = *(const float4*)&sb[(size_t)(d * RR + sl) * 4];
    const int nE = end - start;
    float m0 = -1e30f, m1 = -1e30f, m2 = -1e30f, m3 = -1e30f;
    float l0 = 0.f, l1 = 0.f, l2 = 0.f, l3 = 0.f;
    if (nE <= 16) {
        float a0, a1, a2, a3;
        if (sl < nE) {
            int sr = srlist[start + sl];
            int r = sr & 7;
            float4 tj = *(const float4*)&tb[(size_t)sr * 4];
            a0 = sbs[grp][r][0] + tj.x; a0 = a0 >= 0.f ? a0 : 0.2f * a0;
            a1 = sbs[grp][r][1] + tj.y; a1 = a1 >= 0.f ? a1 : 0.2f * a1;
            a2 = sbs[grp][r][2] + tj.z; a2 = a2 >= 0.f ? a2 : 0.2f * a2;
            a3 = sbs[grp][r][3] + tj.w; a3 = a3 >= 0.f ? a3 : 0.2f * a3;
        } else { a0 = a1 = a2 = a3 = -1e30f; }
        float c0m = a0, c1m = a1, c2m = a2, c3m = a3;
#pragma unroll
        for (int off = 8; off; off >>= 1) {
            c0m = fmaxf(c0m, __shfl_xor(c0m, off));
            c1m = fmaxf(c1m, __shfl_xor(c1m, off));
            c2m = fmaxf(c2m, __shfl_xor(c2m, off));
            c3m = fmaxf(c3m, __shfl_xor(c3m, off));
        }
        m0 = fmaxf(c0m, -1e30f); m1 = c1m; m2 = c2m; m3 = c3m;
        float e0 = 0.f, e1 = 0.f, e2 = 0.f, e3 = 0.f;
        if (sl < nE) {
            e0 = __expf(a0 - m0); e1 = __expf(a1 - m1);
            e2 = __expf(a2 - m2); e3 = __expf(a3 - m3);
            *(float4*)&abuf[(size_t)(start + sl) * 4] = float4{e0, e1, e2, e3};
        }
        l0 = e0; l1 = e1; l2 = e2; l3 = e3;
#pragma unroll
        for (int off = 8; off; off >>= 1) {
            l0 += __shfl_xor(l0, off);
            l1 += __shfl_xor(l1, off);
            l2 += __shfl_xor(l2, off);
            l3 += __shfl_xor(l3, off);
        }
    } else {
        for (int c0 = start; c0 < end; c0 += 16) {
            int n = end - c0; if (n > 16) n = 16;
            float a0, a1, a2, a3;
            if (sl < n) {
                int sr = srlist[c0 + sl];
                int r = sr & 7;
                float4 tj = *(const float4*)&tb[(size_t)sr * 4];
                a0 = sbs[grp][r][0] + tj.x; a0 = a0 >= 0.f ? a0 : 0.2f * a0;
                a1 = sbs[grp][r][1] + tj.y; a1 = a1 >= 0.f ? a1 : 0.2f * a1;
                a2 = sbs[grp][r][2] + tj.z; a2 = a2 >= 0.f ? a2 : 0.2f * a2;
                a3 = sbs[grp][r][3] + tj.w; a3 = a3 >= 0.f ? a3 : 0.2f * a3;
                *(float4*)&abuf[(size_t)(c0 + sl) * 4] = float4{a0, a1, a2, a3};
            } else { a0 = a1 = a2 = a3 = -1e30f; }
            m0 = fmaxf(m0, a0); m1 = fmaxf(m1, a1);
            m2 = fmaxf(m2, a2); m3 = fmaxf(m3, a3);
        }
#pragma unroll
        for (int off = 8; off; off >>= 1) {
            m0 = fmaxf(m0, __shfl_xor(m0, off));
            m1 = fmaxf(m1, __shfl_xor(m1, off));
            m2 = fmaxf(m2, __shfl_xor(m2, off));
            m3 = fmaxf(m3, __shfl_xor(m3, off));
        }
        for (int c0 = start; c0 < end; c0 += 16) {
            int n = end - c0; if (n > 16) n = 16;
            float e0 = 0.f, e1 = 0.f, e2 = 0.f, e3 = 0.f;
            if (sl < n) {
                float4 a = *(const float4*)&abuf[(size_t)(c0 + sl) * 4];
                e0 = __expf(a.x - m0); e1 = __expf(a.y - m1);
                e2 = __expf(a.z - m2); e3 = __expf(a.w - m3);
                *(float4*)&abuf[(size_t)(c0 + sl) * 4] = float4{e0, e1, e2, e3};
            }
            l0 += e0; l1 += e1; l2 += e2; l3 += e3;
        }
#pragma unroll
        for (int off = 8; off; off >>= 1) {
            l0 += __shfl_xor(l0, off);
            l1 += __shfl_xor(l1, off);
            l2 += __shfl_xor(l2, off);
            l3 += __shfl_xor(l3, off);
        }
    }
    if (sl == 0) {
        *(float4*)&linv[(size_t)d * 4] =
            float4{1.f / (l0 + 1e-16f), 1.f / (l1 + 1e-16f),
                   1.f / (l2 + 1e-16f), 1.f / (l3 + 1e-16f)};
    }
}

// ---------------- aggregation pump: gathers only on the critical path ----------------
__global__ __launch_bounds__(256) void k_agg(const int* __restrict__ rowptr,
                                             const int* __restrict__ srlist,
                                             const float* __restrict__ abuf,
                                             const float* __restrict__ linvb,
                                             const bf16* __restrict__ xw,
                                             const void* __restrict__ b,
                                             const void* __restrict__ g,
                                             const void* __restrict__ bb,
                                             const u16* __restrict__ hprev,
                                             u16* __restrict__ hout,
                                             const int* __restrict__ fl) {
    __shared__ int   srs[16][16];
    __shared__ float exs[16][17][4];   // padded: group stride 68 floats
    const int tid = threadIdx.x;
    const int grp = tid >> 4;
    const int sl  = tid & 15;
    const int hh  = sl >> 2;
    const int d   = blockIdx.x * 16 + grp;
    const bool f = fl[0] != 0;
    const int start = rowptr[d], end = rowptr[d + 1];
    float acc[8];
#pragma unroll
    for (int i = 0; i < 8; i++) acc[i] = 0.f;
    for (int c0 = start; c0 < end; c0 += 16) {
        int n = end - c0;
        if (n > 16) n = 16;
        int sr = 0;
        float4 e4 = {0.f, 0.f, 0.f, 0.f};
        if (sl < n) {
            sr = srlist[c0 + sl];
            e4 = *(const float4*)&abuf[(size_t)(c0 + sl) * 4];
        }
        srs[grp][sl] = sr;
        *(float4*)&exs[grp][sl][0] = e4;
        {
            short8 u[8]; float wv[8];
#pragma unroll
            for (int t = 0; t < 8; t++) {
                int s = srs[grp][t];
                wv[t] = exs[grp][t][hh];
                u[t] = *(const short8*)((const u16*)xw + (size_t)s * HIDC + sl * 8);
            }
#pragma unroll
            for (int t = 0; t < 8; t++)
#pragma unroll
                for (int i = 0; i < 8; i++) acc[i] += wv[t] * us2f((u16)u[t][i]);
        }
        if (n > 8) {
            short8 u[8]; float wv[8];
#pragma unroll
            for (int t = 0; t < 8; t++) {
                int s = srs[grp][8 + t];
                wv[t] = exs[grp][8 + t][hh];
                u[t] = *(const short8*)((const u16*)xw + (size_t)s * HIDC + sl * 8);
            }
#pragma unroll
            for (int t = 0; t < 8; t++)
#pragma unroll
                for (int i = 0; i < 8; i++) acc[i] += wv[t] * us2f((u16)u[t][i]);
        }
    }
    float inv = linvb[(size_t)d * 4 + hh];
    float v[8];
#pragma unroll
    for (int i = 0; i < 8; i++)
        v[i] = fmaxf(acc[i] * inv + ldf(b, sl * 8 + i, f), 0.f);
    float sum = 0.f;
#pragma unroll
    for (int i = 0; i < 8; i++) sum += v[i];
#pragma unroll
    for (int off = 8; off; off >>= 1) sum += __shfl_xor(sum, off);
    float mean = sum * (1.f / 128.f);
    float sq = 0.f;
#pragma unroll
    for (int i = 0; i < 8; i++) { v[i] -= mean; sq += v[i] * v[i]; }
#pragma unroll
    for (int off = 8; off; off >>= 1) sq += __shfl_xor(sq, off);
    float rstd = rsqrtf(sq * (1.f / 128.f) + 1e-5f);
    short8 o;
#pragma unroll
    for (int i = 0; i < 8; i++) {
        float y = v[i] * rstd * ldf(g, sl * 8 + i, f) + ldf(bb, sl * 8 + i, f);
        o[i] = (short)f2us(y);
    }
    if (hprev) {
        short8 hv = *(const short8*)&hprev[(size_t)d * HIDC + sl * 8];
#pragma unroll
        for (int i = 0; i < 8; i++)
            o[i] = (short)f2us(us2f((u16)o[i]) + us2f((u16)hv[i]));
    }
    *(short8*)&hout[(size_t)d * HIDC + sl * 8] = o;
}

// ---------------- mw1 + mw2 -> B-fragment order (bf16) for MFMA decode ----------------
__global__ void k_dswz(const void* __restrict__ mw1, const void* __restrict__ mw2,
                       u16* __restrict__ Wf, const int* __restrict__ fl) {
    int idx = blockIdx.x * 256 + threadIdx.x;  // 0..4351
    if (idx >= 4352) return;
    const bool f = fl[0] != 0;
    u16 o[8];
    if (idx < 4096) {
        int c = idx >> 9, q = (idx >> 6) & 7, ln = idx & 63;
        int k0 = q * 32 + (ln >> 4) * 8;
        int nn = c * 16 + (ln & 15);
#pragma unroll
        for (int j = 0; j < 8; j++)
            o[j] = f2us(ldf(mw1, (k0 + j) * HIDC + nn, f));
    } else {
        int fidx = idx - 4096;           // q*64 + lane
        int q = fidx >> 6, ln = fidx & 63;
        int k0 = q * 32 + (ln >> 4) * 8;
        int nn = ln & 15;
#pragma unroll
        for (int j = 0; j < 8; j++)
            o[j] = (nn < 8) ? f2us(ldf(mw2, (k0 + j) * NCL + nn, f)) : (u16)0;
    }
    *(ushort4*)&Wf[idx * 8]     = ushort4{o[0], o[1], o[2], o[3]};
    *(ushort4*)&Wf[idx * 8 + 4] = ushort4{o[4], o[5], o[6], o[7]};
}

// ---------------- decode: barrier-free, direct bf16 A-fragment gathers ----------------
__global__ __launch_bounds__(256) void k_decode2(const u16* __restrict__ h,
                                                 const int* __restrict__ edges,
                                                 const u16* __restrict__ Wf,
                                                 const void* __restrict__ mb1,
                                                 const void* __restrict__ mb2,
                                                 void* __restrict__ out,
                                                 const int* __restrict__ fl) {
    __shared__ u16 zsu[64 * 136];   // 17.4 KB, wave-local rows only
    const int tid = threadIdx.x;
    const bool f = fl[0] != 0;
    const int p0 = blockIdx.x * 64;
    const int w = tid >> 6, lane = tid & 63;
    const int m = 16 * w + (lane & 15);   // row in 64-tile
    const int g = lane >> 4;              // k-group 0..3
    const int na = edges[(size_t)(p0 + m) * 2];
    const int nb = edges[(size_t)(p0 + m) * 2 + 1];
    short8 af[8];
#pragma unroll
    for (int q = 0; q < 8; q++) {
        int k0 = q * 32 + g * 8;          // 0..248
        af[q] = *(const short8*)(h + (size_t)((k0 >> 7) ? nb : na) * HIDC + (k0 & 127));
    }
#pragma unroll
    for (int c = 0; c < 8; c++) {
        floatx4 acc = {0.f, 0.f, 0.f, 0.f};
#pragma unroll
        for (int q = 0; q < 8; q++) {
            short8 bfr = *(const short8*)&Wf[(size_t)(((c * 8 + q) * 64 + lane) * 8)];
            acc = __builtin_amdgcn_mfma_f32_16x16x32_bf16(af[q], bfr, acc, 0, 0, 0);
        }
        int col = c * 16 + (lane & 15);
        float bv = ldf(mb1, col, f);
#pragma unroll
        for (int reg = 0; reg < 4; reg++) {
            int p = 16 * w + (lane >> 4) * 4 + reg;
            float z = acc[reg] + bv;
            zsu[p * 136 + col] = f2us(0.5f * z * (1.f + erff(z * 0.70710678118654752f)));
        }
    }
    // second GEMM: rows wave-local -> no barrier
    floatx4 acc2 = {0.f, 0.f, 0.f, 0.f};
#pragma unroll
    for (int q = 0; q < 4; q++) {
        short8 af2 = *(const short8*)&zsu[m * 136 + q * 32 + g * 8];
        short8 bfr2 = *(const short8*)&Wf[32768 + (size_t)((q * 64 + lane) * 8)];
        acc2 = __builtin_amdgcn_mfma_f32_16x16x32_bf16(af2, bfr2, acc2, 0, 0, 0);
    }
    int col16 = lane & 15;
    if (col16 < 8) {
        float bv2 = ldf(mb2, col16, f);
#pragma unroll
        for (int reg = 0; reg < 4; reg++) {
            int p = 16 * w + (lane >> 4) * 4 + reg;
            float sv = acc2[reg] + bv2;
            size_t oi = (size_t)(p0 + p) * NCL + col16;
            if (f) ((float*)out)[oi] = sv;
            else   ((bf16*)out)[oi] = __float2bfloat16(sv);
        }
    }
}

extern "C" void kernel_launch(void* const* d_in, const int* in_sizes, int n_in,
                              void* d_out, int out_size, void* d_ws, size_t ws_size,
                              hipStream_t stream) {
    (void)in_sizes; (void)n_in; (void)out_size; (void)ws_size;
    const void* x    = d_in[0];
    const int* ei    = (const int*)d_in[1];
    const int* et    = (const int*)d_in[2];
    const int* edges = (const int*)d_in[3];
    const void* w1 = d_in[4];
    const void* q1 = d_in[5];
    const void* k1 = d_in[6];
    const void* b1 = d_in[7];
    const void* w2 = d_in[8];
    const void* q2 = d_in[9];
    const void* k2 = d_in[10];
    const void* b2 = d_in[11];
    const void* ln1g = d_in[12];
    const void* ln1b = d_in[13];
    const void* ln2g = d_in[14];
    const void* ln2b = d_in[15];
    const void* mw1 = d_in[16];
    const void* mb1 = d_in[17];
    const void* mw2 = d_in[18];
    const void* mb2 = d_in[19];

    // workspace layout — within round-3-proven bound (<= 169,425,560 B)
    char* ws = (char*)d_ws;
    bf16* xwb   = (bf16*)ws;                      // [0, 102,400,000)
    u16* Wf     = (u16*)ws;                       // ALIAS xwb: k_dswz runs after last xwb read (69,632 B)
    float* sbuf = (float*)(ws + 102400000);       // 6.4 MB
    float* tbuf = (float*)(ws + 108800000);       // 6.4 MB
    u16* h1     = (u16*)(ws + 115200000);         // 12.8 MB (bf16), region ends 128,000,000
    float* abuf = (float*)(ws + 128000000);       // EE*16 B = 10,240,000 -> ends 138,240,000
    float* linv = (float*)(ws + 138240000);       // NN*16 B = 800,000 -> ends 139,040,000
    int* bsum   = (int*)(ws + 139040000);         // 256 ints (de-aliased from qkw: k_s1q writes both)
    int* boff   = (int*)(ws + 139041024);         // 256 ints
    u16* hsum   = (u16*)(ws + 140800000);         // 12.8 MB (bf16)
    u16* Wf2    = (u16*)(ws + 153600000);         // 589,824 B
    int* rowptr = (int*)(ws + 166400000);         // NN+1 ints
    int* cursor = (int*)(ws + 166600016);         // NN ints
    int* elist  = (int*)(ws + 166800016);         // EE ints (packed sr = src*8+r)
    float* qkw  = (float*)(ws + 169360016);       // 65,536 B -> ends 169,425,552
    int* flags  = (int*)(ws + 169425552);         // 8 B -> ends 169,425,560 (proven)

    // fused preprocessing: 6 launches (was 9)
    k_zs<<<50, 1024, 0, stream>>>((const u16*)x, flags, cursor);
    k_hist<<<2500, 256, 0, stream>>>(ei, cursor);
    k_s1q<<<260, 256, 0, stream>>>(cursor, bsum, w1, w2, q1, k1, q2, k2, qkw, flags);
    k_scan2<<<1, 256, 0, stream>>>(bsum, boff, rowptr);
    k_s3w<<<340, 256, 0, stream>>>(cursor, boff, rowptr, w1, w2, qkw, Wf2, flags);
    k_scatter<<<2500, 256, 0, stream>>>(ei, et, cursor, elist);

    for (int layer = 0; layer < 2; ++layer) {
        const void* b  = layer ? b2 : b1;
        const void* lg = layer ? ln2g : ln1g;
        const void* lb = layer ? ln2b : ln1b;
        k_xw2<<<782, 512, 0, stream>>>(layer ? (const void*)h1 : x, Wf2, xwb,
                                       sbuf, tbuf,
                                       layer ? flags + 1 : flags, layer);
        k_score<<<3125, 256, 0, stream>>>(rowptr, elist, sbuf, tbuf, abuf, linv);
        k_agg<<<3125, 256, 0, stream>>>(rowptr, elist, abuf, linv, xwb,
                                        b, lg, lb,
                                        layer ? h1 : (const u16*)nullptr,
                                        layer ? hsum : h1, flags);
    }
    // decode weight swizzle into xwb space (xwb dead after attn L1)
    k_dswz<<<17, 256, 0, stream>>>(mw1, mw2, Wf, flags);
    k_decode2<<<3125, 256, 0, stream>>>(hsum, edges, Wf, mb1, mb2, d_out, flags);
}